// Round 1
// baseline (26294.803 us; speedup 1.0000x reference)
//
#include <hip/hip_runtime.h>
#include <math.h>

#define B_   64
#define T_   512
#define IN_  64
#define HID_ 256

// ws float offsets:
//   P     : [64 chunks][B][HID]  = 1,048,576 floats (4 MB)
//   rT    : [HID][B]             = 16,384
//   x     : [B][HID]             = 16,384
//   W_inT : [IN][HID]            = 16,384
// total ~4.4 MB

__global__ __launch_bounds__(256) void init_kernel(const float* __restrict__ x0,
                                                   const float* __restrict__ W_in,
                                                   float* __restrict__ x,
                                                   float* __restrict__ rT,
                                                   float* __restrict__ W_inT)
{
    const int b = blockIdx.x;   // doubles as k-index for W_inT (both 64)
    const int i = threadIdx.x;  // 0..255
    const float xv = x0[b * HID_ + i];
    x[b * HID_ + i] = xv;
    rT[i * B_ + b] = tanhf(xv);
    // W_inT[k][i] = W_in[i][k]
    W_inT[b * HID_ + i] = W_in[i * IN_ + b];
}

// C[i,b] partial = sum over jk-chunk of W2d[i,jk] * (rT[j][b]*rT[k][b])
// grid = 256 blocks: 4 i-tiles (64 i each) x 64 chunks (K=1024 = 4 j's x 256 k)
__global__ __launch_bounds__(256) void gemm_step(const float* __restrict__ W,   // W_hh [256][65536]
                                                 const float* __restrict__ rT,  // [256][64]
                                                 float* __restrict__ P)         // [64][64][256]
{
    __shared__ float Ws[64 * 68];   // [kk][i_local], stride 68 keeps float4 16B-aligned, banks spread
    __shared__ float Gs[64 * 64];   // [kk][b]

    const int tid = threadIdx.x;
    const int it  = blockIdx.x >> 6;   // i-tile 0..3
    const int c   = blockIdx.x & 63;   // chunk 0..63
    const int i0  = it << 6;
    const int tx  = tid & 15;          // b-quad
    const int ty  = tid >> 4;          // i-quad (0..15)
    const int bl  = tid & 63;          // b-lane for Gs fill
    const int kq  = tid >> 6;          // 0..3

    float acc[4][4];
    #pragma unroll
    for (int bb = 0; bb < 4; ++bb)
        #pragma unroll
        for (int ii = 0; ii < 4; ++ii) acc[bb][ii] = 0.f;

    for (int tt = 0; tt < 16; ++tt) {
        const int j  = (c << 2) + (tt >> 2);  // current j row
        const int kb = (tt & 3) << 6;         // k-base within j
        __syncthreads();
        // stage W tile: 64 i x 64 k, transposed to Ws[kk][i]
        #pragma unroll
        for (int r = 0; r < 4; ++r) {
            const int f   = (r << 8) + tid;   // 0..1023 float4 slots
            const int row = f >> 4;           // i_local 0..63
            const int c4  = f & 15;           // float4 col
            const float4 w = *(const float4*)(W + (size_t)(i0 + row) * 65536u
                                                + ((size_t)j << 8) + kb + (c4 << 2));
            Ws[(c4 * 4 + 0) * 68 + row] = w.x;
            Ws[(c4 * 4 + 1) * 68 + row] = w.y;
            Ws[(c4 * 4 + 2) * 68 + row] = w.z;
            Ws[(c4 * 4 + 3) * 68 + row] = w.w;
        }
        // stage G tile: Gs[kk][b] = rT[j][b] * rT[kb+kk][b]
        const float rj = rT[(j << 6) + bl];
        #pragma unroll
        for (int r = 0; r < 16; ++r) {
            const int kk = (r << 2) + kq;
            Gs[(kk << 6) + bl] = rj * rT[((kb + kk) << 6) + bl];
        }
        __syncthreads();
        #pragma unroll
        for (int kk = 0; kk < 64; ++kk) {
            const float4 a = *(const float4*)&Ws[kk * 68 + (ty << 2)];
            const float4 g = *(const float4*)&Gs[(kk << 6) + (tx << 2)];
            const float av[4] = {a.x, a.y, a.z, a.w};
            const float gv[4] = {g.x, g.y, g.z, g.w};
            #pragma unroll
            for (int bb = 0; bb < 4; ++bb)
                #pragma unroll
                for (int ii = 0; ii < 4; ++ii)
                    acc[bb][ii] += gv[bb] * av[ii];
        }
    }
    // write partials P[c][b][i]: float4 over i -> 64B-coalesced per tx-group
    float* Pc = P + (c << 14) + i0 + (ty << 2);
    #pragma unroll
    for (int bb = 0; bb < 4; ++bb) {
        const float4 v = make_float4(acc[bb][0], acc[bb][1], acc[bb][2], acc[bb][3]);
        *(float4*)(Pc + (((tx << 2) + bb) << 8)) = v;
    }
}

// reduce partials + input proj + state update; grid 256 = (b, i-quarter), 64 threads
__global__ __launch_bounds__(64) void combine_step(const float* __restrict__ P,
                                                   const float* __restrict__ noise,
                                                   const float* __restrict__ u,
                                                   const float* __restrict__ W_inT,
                                                   const float* __restrict__ b_in,
                                                   float* __restrict__ x,
                                                   float* __restrict__ rT,
                                                   float* __restrict__ traj,
                                                   int t)
{
    const int b = blockIdx.x >> 2;
    const int i = ((blockIdx.x & 3) << 6) + threadIdx.x;

    __shared__ float u_s[64];
    u_s[threadIdx.x] = u[b * (T_ * IN_) + t * IN_ + threadIdx.x];
    __syncthreads();

    float s0 = 0.f, s1 = 0.f, s2 = 0.f, s3 = 0.f;
    #pragma unroll
    for (int c4 = 0; c4 < 16; ++c4) {
        s0 += P[(c4 * 4 + 0) * 16384 + b * 256 + i];
        s1 += P[(c4 * 4 + 1) * 16384 + b * 256 + i];
        s2 += P[(c4 * 4 + 2) * 16384 + b * 256 + i];
        s3 += P[(c4 * 4 + 3) * 16384 + b * 256 + i];
    }
    const float hidden = (s0 + s1) + (s2 + s3);

    float inp = b_in[i];
    #pragma unroll
    for (int k = 0; k < 64; ++k) inp += u_s[k] * W_inT[k * 256 + i];

    const float xo = x[b * 256 + i];
    const float n  = noise[t * (B_ * HID_) + b * 256 + i];
    // x + 0.05*n + 0.2*(-x + hidden + inp)
    const float xn = 0.8f * xo + 0.05f * n + 0.2f * (hidden + inp);

    x[b * 256 + i] = xn;
    traj[(size_t)b * (T_ * HID_) + t * HID_ + i] = xn;
    rT[i * 64 + b] = tanhf(xn);
}

__global__ __launch_bounds__(256) void copy_xfinal(const float* __restrict__ x,
                                                   float* __restrict__ xf)
{
    const int idx = blockIdx.x * 256 + threadIdx.x;
    xf[idx] = x[idx];
}

// out[b,t,o] = sum_i tanh(traj[b,t,i]) * W_out[o,i] + b_out[o]
// grid 2048 blocks: (b, 16-row t-group), 256 threads = 4 row-quads x 64 o
__global__ __launch_bounds__(256) void output_kernel(const float* __restrict__ traj,
                                                     const float* __restrict__ W_out,
                                                     const float* __restrict__ b_out,
                                                     float* __restrict__ out)
{
    __shared__ float r_s[16 * 256];  // [row][i]
    __shared__ float Wt[64 * 65];    // [i_local][o], pad 65 breaks bank conflict

    const int tid = threadIdx.x;
    const int b   = blockIdx.x >> 5;
    const int t0  = (blockIdx.x & 31) << 4;

    #pragma unroll
    for (int r = 0; r < 16; ++r) {
        r_s[r * 256 + tid] = tanhf(traj[(size_t)b * (T_ * HID_) + (t0 + r) * HID_ + tid]);
    }

    const int o  = tid & 63;
    const int rg = tid >> 6;  // 0..3  (one wave per rg)
    float acc0 = b_out[o];
    float acc1 = acc0, acc2 = acc0, acc3 = acc0;

    for (int ib = 0; ib < 4; ++ib) {
        __syncthreads();
        #pragma unroll
        for (int r = 0; r < 16; ++r) {
            const int f  = (r << 8) + tid;
            const int oo = f >> 6;
            const int il = f & 63;
            Wt[il * 65 + oo] = W_out[oo * 256 + (ib << 6) + il];
        }
        __syncthreads();
        #pragma unroll 16
        for (int il = 0; il < 64; ++il) {
            const float w = Wt[il * 65 + o];
            const int i = (ib << 6) + il;
            acc0 += r_s[(rg * 4 + 0) * 256 + i] * w;
            acc1 += r_s[(rg * 4 + 1) * 256 + i] * w;
            acc2 += r_s[(rg * 4 + 2) * 256 + i] * w;
            acc3 += r_s[(rg * 4 + 3) * 256 + i] * w;
        }
    }
    float* ob = out + b * (T_ * IN_) + (t0 + (rg << 2)) * IN_ + o;
    ob[0 * IN_] = acc0;
    ob[1 * IN_] = acc1;
    ob[2 * IN_] = acc2;
    ob[3 * IN_] = acc3;
}

extern "C" void kernel_launch(void* const* d_in, const int* in_sizes, int n_in,
                              void* d_out, int out_size, void* d_ws, size_t ws_size,
                              hipStream_t stream)
{
    const float* u     = (const float*)d_in[0];
    const float* x0    = (const float*)d_in[1];
    const float* noise = (const float*)d_in[2];
    const float* W_hh  = (const float*)d_in[3];
    const float* W_in  = (const float*)d_in[4];
    const float* b_in  = (const float*)d_in[5];
    const float* W_out = (const float*)d_in[6];
    const float* b_out = (const float*)d_in[7];

    float* out  = (float*)d_out;
    float* xf   = out + 2097152;            // [B][HID]
    float* traj = out + 2097152 + 16384;    // [B][T][HID]

    float* ws    = (float*)d_ws;
    float* P     = ws;
    float* rT    = ws + 1048576;
    float* x     = ws + 1048576 + 16384;
    float* W_inT = ws + 1048576 + 32768;

    init_kernel<<<64, 256, 0, stream>>>(x0, W_in, x, rT, W_inT);
    for (int t = 0; t < T_; ++t) {
        gemm_step<<<256, 256, 0, stream>>>(W_hh, rT, P);
        combine_step<<<256, 64, 0, stream>>>(P, noise, u, W_inT, b_in, x, rT, traj, t);
    }
    copy_xfinal<<<64, 256, 0, stream>>>(x, xf);
    output_kernel<<<2048, 256, 0, stream>>>(traj, W_out, b_out, out);
}

// Round 2
// 14200.867 us; speedup vs baseline: 1.8516x; 1.8516x over previous
//
#include <hip/hip_runtime.h>
#include <math.h>

#define B_   64
#define T_   512
#define IN_  64
#define HID_ 256
#define KTOT 65536   // HID*HID

typedef __attribute__((ext_vector_type(8))) short  short8;
typedef __attribute__((ext_vector_type(4))) float  floatx4;

__device__ __forceinline__ unsigned short f2bf(float f) {
    unsigned int u = __float_as_uint(f);
    u += 0x7FFFu + ((u >> 16) & 1u);          // round-to-nearest-even
    return (unsigned short)(u >> 16);
}
__device__ __forceinline__ float bf2f(unsigned short s) {
    return __uint_as_float(((unsigned int)s) << 16);
}

// ---- once per launch: W_hh fp32 -> bf16 ----------------------------------
__global__ __launch_bounds__(256) void conv_w(const float* __restrict__ W,
                                              unsigned short* __restrict__ Wb)
{
    const size_t idx = ((size_t)blockIdx.x * 256 + threadIdx.x) * 4;
    const float4 v = *(const float4*)(W + idx);
    unsigned int lo = (unsigned int)f2bf(v.x) | ((unsigned int)f2bf(v.y) << 16);
    unsigned int hi = (unsigned int)f2bf(v.z) | ((unsigned int)f2bf(v.w) << 16);
    *(uint2*)(Wb + idx) = make_uint2(lo, hi);
}

// ---- init: x, rB(bf16), W_inT --------------------------------------------
__global__ __launch_bounds__(256) void init_kernel(const float* __restrict__ x0,
                                                   const float* __restrict__ W_in,
                                                   float* __restrict__ x,
                                                   unsigned short* __restrict__ rB,
                                                   float* __restrict__ W_inT)
{
    const int b = blockIdx.x;   // doubles as k for W_inT (both 64)
    const int i = threadIdx.x;
    const float xv = x0[b * HID_ + i];
    x[b * HID_ + i]  = xv;
    rB[b * HID_ + i] = f2bf(tanhf(xv));
    W_inT[b * HID_ + i] = W_in[i * IN_ + b];
}

// ---- per-step bf16 MFMA GEMM ---------------------------------------------
// D[b,i] = sum_k G[b,k] * W^T[k,i],  G[b, j*256+k2] = r[b,j]*r[b,k2]
// grid = 4 i-groups (64 i) x 128 k-slices (Ks=512) = 512 blocks, 256 thr.
// Waves split b: wave w handles b in [16w,16w+16), all 4 i-tiles of the group.
__global__ __launch_bounds__(256) void gemm_step(const unsigned short* __restrict__ Wb,
                                                 const unsigned short* __restrict__ rB,
                                                 float* __restrict__ P)
{
    __shared__ unsigned short A_lds[32768];  // 64 KB: [itile(4)][kc(16)][lane(64)][8]

    const int tid = threadIdx.x;
    const int l   = tid & 63;
    const int w   = tid >> 6;        // wave 0..3
    const int m   = l & 15;
    const int q   = l >> 4;
    const int ig  = blockIdx.x >> 7; // i-group 0..3
    const int c   = blockIdx.x & 127;// k-slice 0..127
    const int i0  = ig << 6;

    // stage W slice: wave w loads i-tile w, rows i0+16w+m, fragment-linear
    {
        const unsigned short* src = Wb + (size_t)(i0 + (w << 4) + m) * KTOT
                                       + (c << 9) + (q << 3);
        unsigned short* dst = &A_lds[(w << 13) + (l << 3)];
        #pragma unroll
        for (int kc = 0; kc < 16; ++kc) {
            uint4 v = *(const uint4*)(src + (kc << 5));
            *(uint4*)(dst + (kc << 9)) = v;
        }
    }

    const int b = (w << 4) + m;                  // this lane's batch row
    const float rj0 = bf2f(rB[b * HID_ + 2 * c]);
    const float rj1 = bf2f(rB[b * HID_ + 2 * c + 1]);
    const unsigned short* rrow = rB + b * HID_ + (q << 3);

    floatx4 acc0 = {0.f, 0.f, 0.f, 0.f};
    floatx4 acc1 = {0.f, 0.f, 0.f, 0.f};
    floatx4 acc2 = {0.f, 0.f, 0.f, 0.f};
    floatx4 acc3 = {0.f, 0.f, 0.f, 0.f};

    __syncthreads();

    #pragma unroll
    for (int kc = 0; kc < 16; ++kc) {
        const float rj = (kc < 8) ? rj0 : rj1;
        const uint4 rv = *(const uint4*)(rrow + ((kc & 7) << 5));
        short8 gfrag;
        {
            unsigned int* gp = (unsigned int*)&gfrag;
            const unsigned short* rs = (const unsigned short*)&rv;
            #pragma unroll
            for (int p = 0; p < 4; ++p) {
                const float lo = bf2f(rs[2 * p])     * rj;
                const float hi = bf2f(rs[2 * p + 1]) * rj;
                gp[p] = (unsigned int)f2bf(lo) | ((unsigned int)f2bf(hi) << 16);
            }
        }
        const unsigned short* ab = &A_lds[(kc << 9) + (l << 3)];
        const short8 w0 = *(const short8*)(ab);
        const short8 w1 = *(const short8*)(ab + 8192);
        const short8 w2 = *(const short8*)(ab + 16384);
        const short8 w3 = *(const short8*)(ab + 24576);
        acc0 = __builtin_amdgcn_mfma_f32_16x16x32_bf16(gfrag, w0, acc0, 0, 0, 0);
        acc1 = __builtin_amdgcn_mfma_f32_16x16x32_bf16(gfrag, w1, acc1, 0, 0, 0);
        acc2 = __builtin_amdgcn_mfma_f32_16x16x32_bf16(gfrag, w2, acc2, 0, 0, 0);
        acc3 = __builtin_amdgcn_mfma_f32_16x16x32_bf16(gfrag, w3, acc3, 0, 0, 0);
    }

    // C layout: row(b_local) = q*4+reg, col(i_local) = m
    #pragma unroll
    for (int reg = 0; reg < 4; ++reg) {
        float* dst = P + (c << 14) + ((w << 4) + (q << 2) + reg) * HID_ + i0 + m;
        dst[0]  = acc0[reg];
        dst[16] = acc1[reg];
        dst[32] = acc2[reg];
        dst[48] = acc3[reg];
    }
}

// ---- combine: reduce 128 partials + input proj + state update ------------
// grid 256 = (b, i-quarter), 64 threads
__global__ __launch_bounds__(64) void combine_step(const float* __restrict__ P,
                                                   const float* __restrict__ noise,
                                                   const float* __restrict__ u,
                                                   const float* __restrict__ W_inT,
                                                   const float* __restrict__ b_in,
                                                   float* __restrict__ x,
                                                   unsigned short* __restrict__ rB,
                                                   float* __restrict__ traj,
                                                   int t)
{
    const int b = blockIdx.x >> 2;
    const int i = ((blockIdx.x & 3) << 6) + threadIdx.x;

    __shared__ float u_s[64];
    u_s[threadIdx.x] = u[b * (T_ * IN_) + t * IN_ + threadIdx.x];
    __syncthreads();

    const float* Pp = P + b * HID_ + i;
    float s0 = 0.f, s1 = 0.f, s2 = 0.f, s3 = 0.f;
    #pragma unroll 4
    for (int cc = 0; cc < 128; cc += 4) {
        s0 += Pp[(cc + 0) * 16384];
        s1 += Pp[(cc + 1) * 16384];
        s2 += Pp[(cc + 2) * 16384];
        s3 += Pp[(cc + 3) * 16384];
    }
    const float hidden = (s0 + s1) + (s2 + s3);

    float inp = b_in[i];
    #pragma unroll
    for (int k = 0; k < 64; ++k) inp += u_s[k] * W_inT[k * HID_ + i];

    const float xo = x[b * HID_ + i];
    const float n  = noise[t * (B_ * HID_) + b * HID_ + i];
    const float xn = 0.8f * xo + 0.05f * n + 0.2f * (hidden + inp);

    x[b * HID_ + i] = xn;
    traj[(size_t)b * (T_ * HID_) + t * HID_ + i] = xn;
    rB[b * HID_ + i] = f2bf(tanhf(xn));
}

__global__ __launch_bounds__(256) void copy_xfinal(const float* __restrict__ x,
                                                   float* __restrict__ xf)
{
    const int idx = blockIdx.x * 256 + threadIdx.x;
    xf[idx] = x[idx];
}

// ---- output projection (unchanged from R1, fp32) -------------------------
__global__ __launch_bounds__(256) void output_kernel(const float* __restrict__ traj,
                                                     const float* __restrict__ W_out,
                                                     const float* __restrict__ b_out,
                                                     float* __restrict__ out)
{
    __shared__ float r_s[16 * 256];
    __shared__ float Wt[64 * 65];

    const int tid = threadIdx.x;
    const int b   = blockIdx.x >> 5;
    const int t0  = (blockIdx.x & 31) << 4;

    #pragma unroll
    for (int r = 0; r < 16; ++r) {
        r_s[r * 256 + tid] = tanhf(traj[(size_t)b * (T_ * HID_) + (t0 + r) * HID_ + tid]);
    }

    const int o  = tid & 63;
    const int rg = tid >> 6;
    float acc0 = b_out[o];
    float acc1 = acc0, acc2 = acc0, acc3 = acc0;

    for (int ib = 0; ib < 4; ++ib) {
        __syncthreads();
        #pragma unroll
        for (int r = 0; r < 16; ++r) {
            const int f  = (r << 8) + tid;
            const int oo = f >> 6;
            const int il = f & 63;
            Wt[il * 65 + oo] = W_out[oo * 256 + (ib << 6) + il];
        }
        __syncthreads();
        #pragma unroll 16
        for (int il = 0; il < 64; ++il) {
            const float w = Wt[il * 65 + o];
            const int i = (ib << 6) + il;
            acc0 += r_s[(rg * 4 + 0) * 256 + i] * w;
            acc1 += r_s[(rg * 4 + 1) * 256 + i] * w;
            acc2 += r_s[(rg * 4 + 2) * 256 + i] * w;
            acc3 += r_s[(rg * 4 + 3) * 256 + i] * w;
        }
    }
    float* ob = out + b * (T_ * IN_) + (t0 + (rg << 2)) * IN_ + o;
    ob[0 * IN_] = acc0;
    ob[1 * IN_] = acc1;
    ob[2 * IN_] = acc2;
    ob[3 * IN_] = acc3;
}

extern "C" void kernel_launch(void* const* d_in, const int* in_sizes, int n_in,
                              void* d_out, int out_size, void* d_ws, size_t ws_size,
                              hipStream_t stream)
{
    const float* u     = (const float*)d_in[0];
    const float* x0    = (const float*)d_in[1];
    const float* noise = (const float*)d_in[2];
    const float* W_hh  = (const float*)d_in[3];
    const float* W_in  = (const float*)d_in[4];
    const float* b_in  = (const float*)d_in[5];
    const float* W_out = (const float*)d_in[6];
    const float* b_out = (const float*)d_in[7];

    float* out  = (float*)d_out;
    float* xf   = out + 2097152;            // [B][HID]
    float* traj = out + 2097152 + 16384;    // [B][T][HID]

    // ws layout (float offsets):
    //   P     : 0          .. 2,097,152   (8 MB, 128 slices x 64 x 256)
    //   Wb    : 2,097,152  .. +8,388,608  float-slots (16.7M ushorts, 32 MB)
    //   rB    : +8192 float-slots (16384 ushorts)
    //   x     : 16384 floats
    //   W_inT : 16384 floats
    float* ws = (float*)d_ws;
    float*          P     = ws;
    unsigned short* Wb    = (unsigned short*)(ws + 2097152);
    unsigned short* rB    = (unsigned short*)(ws + 2097152 + 8388608);
    float*          x     = ws + 2097152 + 8388608 + 8192;
    float*          W_inT = x + 16384;

    conv_w<<<16384, 256, 0, stream>>>(W_hh, Wb);
    init_kernel<<<64, 256, 0, stream>>>(x0, W_in, x, rB, W_inT);
    for (int t = 0; t < T_; ++t) {
        gemm_step<<<512, 256, 0, stream>>>(Wb, rB, P);
        combine_step<<<256, 64, 0, stream>>>(P, noise, u, W_inT, b_in, x, rB, traj, t);
    }
    copy_xfinal<<<64, 256, 0, stream>>>(x, xf);
    output_kernel<<<2048, 256, 0, stream>>>(traj, W_out, b_out, out);
}